// Round 12
// baseline (332.897 us; speedup 1.0000x reference)
//
#include <hip/hip_runtime.h>
#include <hip/hip_bf16.h>
#include <type_traits>

#define BQ   256
#define NTR  50000
#define DD   3072
#define NSP  50048          // padded N stride (multiple of 64)
#define NBLK 782
#define CAP  4096
#define DELTA 18.0f

typedef __fp16 f16;
typedef __fp16 f16x2 __attribute__((ext_vector_type(2)));
typedef __fp16 f16x8 __attribute__((ext_vector_type(8)));
typedef float  f32x4 __attribute__((ext_vector_type(4)));

__device__ __forceinline__ void gload_lds16(const void* g, void* l) {
    __builtin_amdgcn_global_load_lds(
        (const __attribute__((address_space(1))) unsigned int*)g,
        (__attribute__((address_space(3))) unsigned int*)l, 16, 0, 0);
}

// ---------------- P0: convert x (f32) -> fp16, fragment-major pack ----------------
__global__ __launch_bounds__(256) void kx(const float* __restrict__ x, f16* __restrict__ xp) {
    const int t = blockIdx.x * 256 + threadIdx.x;   // t = g*256 + r, grid = 384*256
    const int g = t >> 8, r = t & 255;
    const f32x4* src = (const f32x4*)(x + (size_t)r * DD + (g << 3));
    f32x4 a = src[0], b = src[1];
    union { f16x2 h2[4]; f16x8 h8; } u;
    u.h2[0] = __builtin_amdgcn_cvt_pkrtz(a[0], a[1]);
    u.h2[1] = __builtin_amdgcn_cvt_pkrtz(a[2], a[3]);
    u.h2[2] = __builtin_amdgcn_cvt_pkrtz(b[0], b[1]);
    u.h2[3] = __builtin_amdgcn_cvt_pkrtz(b[2], b[3]);
    ((f16x8*)xp)[t] = u.h8;
}

// ---------------- P1: S = X*Y^T - 0.5*|y|^2, BK=256, global_load_lds y-staging ----------------
// Each y-load instruction = 64 lanes x 16B = 1KB CONTIGUOUS from ONE row (fill-grain
// DRAM requests; every prior variant issued 16B/lane scattered across rows). y goes
// f32 straight to LDS (no VGPR roundtrip); swizzled-linear layout via pre-swizzled
// per-lane global addresses; cvt to f16 at bf-build. af issued before the y batch
// (sched_barrier-pinned) so af waits = vmcnt(8), leaving y in flight.
__global__ __launch_bounds__(512, 2) void kqk(
    const f16* __restrict__ xp, const float* __restrict__ y,
    float* __restrict__ S, float* __restrict__ pmax) {
    __shared__ char Bs[2][65536];   // 64 rows x 1024 B (f32), 16B-unit XOR-swizzle

    const int tid = threadIdx.x;
    const int blk = blockIdx.x;
    const int n0  = blk * 64;
    const int w = tid >> 6, l = tid & 63;
    const int l15 = l & 15, lg = l >> 4;

    // wave w stages rows 8w+j; lane l covers swizzled 16B unit ((l^j)*16)
    const char* ysrc[8];
    #pragma unroll
    for (int j = 0; j < 8; ++j) {
        int row  = n0 + (w << 3) + j;
        int rowc = row < NTR ? row : NTR - 1;
        ysrc[j] = (const char*)(y + (size_t)rowc * DD) + (((l << 4) ^ (j << 4)));
    }

    auto stage = [&](int buf, int ks) {
        #pragma unroll
        for (int j = 0; j < 8; ++j)
            gload_lds16(ysrc[j] + (ks << 10), &Bs[buf][(((w << 3) + j) << 10)]);
    };

    // prologue: y(0) -> buf 0
    stage(0, 0);
    __syncthreads();

    const f16x8* ap = (const f16x8*)xp;
    const int arow = (w << 5) + l15;        // wave w owns query rows w*32..w*32+31
    f32x4 acc[2][4] = {};
    float y2a[4] = {0.f, 0.f, 0.f, 0.f};

    for (int ks = 0; ks < 12; ++ks) {
        const int cur = ks & 1;
        // A fragments from L2 — all 8 kk upfront, BEFORE the y batch
        f16x8 af[8][2];
        #pragma unroll
        for (int kk = 0; kk < 8; ++kk)
            #pragma unroll
            for (int fm = 0; fm < 2; ++fm)
                af[kk][fm] = ap[(size_t)((ks << 5) + (kk << 2) + lg) * 256 + arow + (fm << 4)];
        __builtin_amdgcn_sched_barrier(0);
        if (ks < 11) stage(cur ^ 1, ks + 1);
        __builtin_amdgcn_sched_barrier(0);
        const char* Bc = Bs[cur];
        #pragma unroll
        for (int kk = 0; kk < 8; ++kk) {
            f16x8 bf[4];
            #pragma unroll
            for (int fn = 0; fn < 4; ++fn) {
                const int r = (fn << 4) + l15;
                const int m = (r & 7) << 4;
                const int p = (kk << 7) + (lg << 5);
                f32x4 lo = *(const f32x4*)(Bc + (r << 10) + (p ^ m));
                f32x4 hi = *(const f32x4*)(Bc + (r << 10) + ((p + 16) ^ m));
                if (w == 0) {
                    y2a[fn] += lo[0]*lo[0] + lo[1]*lo[1] + lo[2]*lo[2] + lo[3]*lo[3]
                             + hi[0]*hi[0] + hi[1]*hi[1] + hi[2]*hi[2] + hi[3]*hi[3];
                }
                union { f16x2 h2[4]; f16x8 h8; } u;
                u.h2[0] = __builtin_amdgcn_cvt_pkrtz(lo[0], lo[1]);
                u.h2[1] = __builtin_amdgcn_cvt_pkrtz(lo[2], lo[3]);
                u.h2[2] = __builtin_amdgcn_cvt_pkrtz(hi[0], hi[1]);
                u.h2[3] = __builtin_amdgcn_cvt_pkrtz(hi[2], hi[3]);
                bf[fn] = u.h8;
            }
            #pragma unroll
            for (int fm = 0; fm < 2; ++fm)
                #pragma unroll
                for (int fn = 0; fn < 4; ++fn)
                    acc[fm][fn] = __builtin_amdgcn_mfma_f32_16x16x32_f16(af[kk][fm], bf[fn], acc[fm][fn], 0, 0, 0);
        }
        __syncthreads();
    }

    // epilogue: y2 (wave 0 partials over lg-slices) -> LDS broadcast
    float* lys = (float*)&Bs[0][0];
    #pragma unroll
    for (int fn = 0; fn < 4; ++fn) {
        float v = y2a[fn];
        v += __shfl_xor(v, 16, 64);
        v += __shfl_xor(v, 32, 64);
        y2a[fn] = v;
    }
    if (w == 0 && lg == 0) {
        #pragma unroll
        for (int fn = 0; fn < 4; ++fn) lys[(fn << 4) + l15] = y2a[fn];
    }
    __syncthreads();
    float ly2[4];
    #pragma unroll
    for (int fn = 0; fn < 4; ++fn) ly2[fn] = 0.5f * lys[(fn << 4) + l15];
    // per-row max over this block's 64 cols (pad cols masked)
    #pragma unroll
    for (int fm = 0; fm < 2; ++fm) {
        #pragma unroll
        for (int j = 0; j < 4; ++j) {
            float rm = -3.4e38f;
            #pragma unroll
            for (int fn = 0; fn < 4; ++fn) {
                int col = n0 + (fn << 4) + l15;
                float sc = acc[fm][fn][j] - ly2[fn];
                rm = (col < NTR) ? fmaxf(rm, sc) : rm;
            }
            #pragma unroll
            for (int off = 1; off < 16; off <<= 1) rm = fmaxf(rm, __shfl_xor(rm, off, 64));
            if (l15 == 0)
                pmax[(size_t)((w << 5) + (fm << 4) + (lg << 2) + j) * NBLK + blk] = rm;
        }
    }
    // S = x.y - 0.5|y|^2
    #pragma unroll
    for (int fm = 0; fm < 2; ++fm) {
        int row0 = (w << 5) + (fm << 4) + (lg << 2);
        #pragma unroll
        for (int fn = 0; fn < 4; ++fn) {
            int col = n0 + (fn << 4) + l15;
            float* sp = S + (size_t)row0 * NSP + col;
            sp[0]               = acc[fm][fn][0] - ly2[fn];
            sp[NSP]             = acc[fm][fn][1] - ly2[fn];
            sp[2 * (size_t)NSP] = acc[fm][fn][2] - ly2[fn];
            sp[3 * (size_t)NSP] = acc[fm][fn][3] - ly2[fn];
        }
    }
}

// ---------------- P2: row max from pmax + candidate selection ----------------
__global__ __launch_bounds__(256) void ksel(
    const float* __restrict__ S, const float* __restrict__ pmax,
    const float* __restrict__ sig, unsigned* __restrict__ cnt,
    unsigned* __restrict__ cand) {
    __shared__ float red[4];
    const int b = blockIdx.x, tid = threadIdx.x;
    const float s2 = sig[b] * sig[b];
    const float* pm = pmax + (size_t)b * NBLK;
    float mx = -3.4e38f;
    for (int i = tid; i < NBLK; i += 256) mx = fmaxf(mx, pm[i]);
    #pragma unroll
    for (int o = 1; o < 64; o <<= 1) mx = fmaxf(mx, __shfl_xor(mx, o, 64));
    if ((tid & 63) == 0) red[tid >> 6] = mx;
    __syncthreads();
    mx = fmaxf(fmaxf(red[0], red[1]), fmaxf(red[2], red[3]));
    const float thr = mx - DELTA * s2;
    const f32x4* rowv = (const f32x4*)(S + (size_t)b * NSP);
    for (int i = tid; i < 12500; i += 256) {
        f32x4 s = rowv[i];
        #pragma unroll
        for (int j = 0; j < 4; ++j) {
            if (s[j] >= thr) {
                unsigned idx = atomicAdd(&cnt[b], 1u);
                if (idx < CAP) cand[(size_t)b * CAP + idx] = (unsigned)(4 * i + j);
            }
        }
    }
}

// ---------------- P3: fused exact rescoring + online softmax + PV ----------------
__global__ __launch_bounds__(512) void kpv(
    const float* __restrict__ x, const float* __restrict__ y,
    const float* __restrict__ sig, const unsigned* __restrict__ cnt,
    const unsigned* __restrict__ cand, float* __restrict__ out) {
    __shared__ float xs[DD];
    __shared__ unsigned ci[CAP];
    __shared__ float om[8], ol[8];
    __shared__ float sumv[DD];
    const int b = blockIdx.x, tid = threadIdx.x;
    const int c = (int)(cnt[b] < (unsigned)CAP ? cnt[b] : (unsigned)CAP);
    const float s2 = sig[b] * sig[b];
    const float isc = -0.5f / s2;
    for (int i = tid; i < DD; i += 512) xs[i] = x[(size_t)b * DD + i];
    for (int i = tid; i < c; i += 512) ci[i] = cand[(size_t)b * CAP + i];
    __syncthreads();
    const int w = tid >> 6, l = tid & 63;
    const f32x4* xr = (const f32x4*)xs;

    f32x4 o[12] = {};
    float m = -3.4e38f, ll = 0.f;
    f32x4 A[12], Bv[12];

    auto LD = [&](f32x4* dst, int i) {
        const f32x4* yr = (const f32x4*)(y + (size_t)ci[i] * DD);
        #pragma unroll
        for (int j = 0; j < 12; ++j) dst[j] = yr[(j << 6) + l];
    };
    auto PROC = [&](f32x4* src) {
        float d2 = 0.f;
        #pragma unroll
        for (int j = 0; j < 12; ++j) {
            f32x4 xv = xr[(j << 6) + l];
            float a0 = xv[0]-src[j][0], a1 = xv[1]-src[j][1],
                  a2 = xv[2]-src[j][2], a3 = xv[3]-src[j][3];
            d2 += a0*a0 + a1*a1 + a2*a2 + a3*a3;
        }
        #pragma unroll
        for (int off = 1; off < 64; off <<= 1) d2 += __shfl_xor(d2, off, 64);
        float s = d2 * isc;
        float mn = fmaxf(m, s);
        float f = __expf(m - mn);
        float wi = __expf(s - mn);
        #pragma unroll
        for (int j = 0; j < 12; ++j) o[j] = o[j] * f + wi * src[j];
        ll = ll * f + wi;
        m = mn;
    };

    int i = w;
    if (i < c) LD(A, i);
    for (; i < c; i += 16) {
        int i2 = i + 8;
        if (i2 < c) LD(Bv, i2);
        PROC(A);
        if (i2 < c) {
            if (i + 16 < c) LD(A, i + 16);
            PROC(Bv);
        }
    }
    om[w] = m; ol[w] = ll;
    __syncthreads();
    float M = om[0];
    #pragma unroll
    for (int ww = 1; ww < 8; ++ww) M = fmaxf(M, om[ww]);
    float Ls = 0.f;
    #pragma unroll
    for (int ww = 0; ww < 8; ++ww) Ls += ol[ww] * __expf(om[ww] - M);
    const float fw = __expf(m - M);
    f32x4* sv = (f32x4*)sumv;
    if (w == 0) {
        #pragma unroll
        for (int j = 0; j < 12; ++j) sv[(j << 6) + l] = o[j] * fw;
    }
    __syncthreads();
    for (int ww = 1; ww < 8; ++ww) {
        if (w == ww) {
            #pragma unroll
            for (int j = 0; j < 12; ++j) sv[(j << 6) + l] += o[j] * fw;
        }
        __syncthreads();
    }
    const float inv = 1.f / Ls;
    f32x4* od = (f32x4*)(out + (size_t)b * DD);
    for (int t = tid; t < 768; t += 512) od[t] = sv[t] * inv;
}

extern "C" void kernel_launch(void* const* d_in, const int* in_sizes, int n_in,
                              void* d_out, int out_size, void* d_ws, size_t ws_size,
                              hipStream_t stream) {
    const float* x   = (const float*)d_in[0];
    const float* sig = (const float*)d_in[1];
    const float* y   = (const float*)d_in[2];
    float* out = (float*)d_out;
    char* ws = (char*)d_ws;
    f16*      xp   = (f16*)(ws);                  // 1,572,864
    unsigned* cnt  = (unsigned*)(ws + 1572864);   // 1,024
    unsigned* cand = (unsigned*)(ws + 1573888);   // 4,194,304
    float*    pmax = (float*)(ws + 5768192);      // 256*782*4 = 800,768
    float*    S    = (float*)(ws + 6568960);      // 256*50048*4 = 51,249,152

    (void)hipMemsetAsync(cnt, 0, 256 * sizeof(unsigned), stream);
    kx  <<<384, 256, 0, stream>>>(x, xp);
    kqk <<<NBLK, 512, 0, stream>>>(xp, y, S, pmax);
    ksel<<<256, 256, 0, stream>>>(S, pmax, sig, cnt, cand);
    kpv <<<256, 512, 0, stream>>>(x, y, sig, cnt, cand, out);
}